// Round 6
// baseline (357.717 us; speedup 1.0000x reference)
//
#include <hip/hip_runtime.h>
#include <stdint.h>

// Problem constants
#define B_   4
#define S_   2048
#define H_   16
#define D_   64
#define DM_  1024
#define NTOK (B_ * S_)          // 8192 tokens

typedef __attribute__((ext_vector_type(8))) short short8;   // 8 bf16 (4 VGPRs)
typedef __attribute__((ext_vector_type(4))) float floatx4;  // MFMA C/D

__device__ inline unsigned short f2bf(float f) {
  // RNE float -> bf16 (finite inputs)
  unsigned int u = __float_as_uint(f);
  u += 0x7FFFu + ((u >> 16) & 1u);
  return (unsigned short)(u >> 16);
}

__device__ inline floatx4 mfma_bf16(short8 a, short8 b, floatx4 c) {
  return __builtin_amdgcn_mfma_f32_16x16x32_bf16(a, b, c, 0, 0, 0);
}

// pack two fp32 into bf16x2 (RTZ: take high 16 bits of each) — one v_perm_b32
__device__ inline unsigned int pack_bf2(float lo, float hi) {
  return __builtin_amdgcn_perm(__float_as_uint(hi), __float_as_uint(lo), 0x07060302u);
}

// async global->LDS, 16B per lane; LDS dest = wave-uniform base + lane*16
__device__ inline void gload_lds16(const unsigned short* g, unsigned short* l) {
  __builtin_amdgcn_global_load_lds(
      (const __attribute__((address_space(1))) unsigned int*)g,
      (__attribute__((address_space(3))) unsigned int*)l, 16, 0, 0);
}

// ---------------------------------------------------------------------------
// fp32 -> bf16 bulk cast of Q, K, V in one dispatch (z selects tensor).
// ---------------------------------------------------------------------------
__global__ __launch_bounds__(256) void cast3_kernel(const float* __restrict__ Q,
                                                    const float* __restrict__ Kf,
                                                    const float* __restrict__ V,
                                                    unsigned short* __restrict__ qB,
                                                    unsigned short* __restrict__ kB,
                                                    unsigned short* __restrict__ vB) {
  const float* in = blockIdx.z == 0 ? Q : blockIdx.z == 1 ? Kf : V;
  unsigned short* out = blockIdx.z == 0 ? qB : blockIdx.z == 1 ? kB : vB;
  const int n4 = NTOK * DM_ / 4;
  for (int i = blockIdx.x * 256 + threadIdx.x; i < n4; i += gridDim.x * 256) {
    float4 v = ((const float4*)in)[i];
    ushort4 o;
    o.x = f2bf(v.x); o.y = f2bf(v.y); o.z = f2bf(v.z); o.w = f2bf(v.w);
    ((ushort4*)out)[i] = o;
  }
}

// ---------------------------------------------------------------------------
// LDS-tiled weight cast+transpose: w[k][n] fp32 [1024x1024] -> wT[n][k] bf16.
// ---------------------------------------------------------------------------
__global__ __launch_bounds__(256) void wt_kernel(const float* __restrict__ w0,
                                                 const float* __restrict__ w1,
                                                 const float* __restrict__ w2,
                                                 const float* __restrict__ w3,
                                                 unsigned short* __restrict__ o0,
                                                 unsigned short* __restrict__ o1,
                                                 unsigned short* __restrict__ o2,
                                                 unsigned short* __restrict__ o3) {
  __shared__ unsigned short T[64 * 68];   // transposed tile [n][k], stride 68
  const float* w = blockIdx.z == 0 ? w0 : blockIdx.z == 1 ? w1 : blockIdx.z == 2 ? w2 : w3;
  unsigned short* o = blockIdx.z == 0 ? o0 : blockIdx.z == 1 ? o1 : blockIdx.z == 2 ? o2 : o3;
  const int tid = threadIdx.x;
  const int R0 = blockIdx.y * 64;   // k-block
  const int C0 = blockIdx.x * 64;   // n-block
  for (int it = 0; it < 16; it++) {
    int lr = it * 4 + (tid >> 6), lc = tid & 63;
    T[lc * 68 + lr] = f2bf(w[(size_t)(R0 + lr) * 1024 + C0 + lc]);
  }
  __syncthreads();
  for (int it = 0; it < 2; it++) {
    int orow = it * 32 + (tid >> 3), oc = (tid & 7) * 8;
    union { ushort4 h[2]; short8 v8; } u;
    u.h[0] = *(const ushort4*)(T + orow * 68 + oc);
    u.h[1] = *(const ushort4*)(T + orow * 68 + oc + 4);
    *(short8*)(o + (size_t)(C0 + orow) * 1024 + R0 + oc) = u.v8;
  }
}

// ---------------------------------------------------------------------------
// bf16 GEMM, 256x128 tile, BK=64, 512 threads (8 waves, 2M x 4N), 2-phase
// double-buffered (proven sync structure; geometry per m248/m230: 8x the
// MFMA-per-barrier of the 128^2/BK=32 structure that plateaued at ~344 TF).
//
// LDS 96 KB: As 2x32KB (256 rows x 64 bf16), Bs 2x16KB (128 rows x 64 bf16).
// Each row = 128B = 8 x 16B chunks; chunk gc of row r at slot gc^(r&7)
// (coalesced staging: 8 lanes cover one 128B row permuted; frag reads are
// conflict-free per 8-lane cycle).
//
// Per iter per wave: 6 gload_lds (stage next), 4+16 ds_read_b128, 32 MFMA.
// 16 K-iters. Wave tile 128x32: frags af[8] x bfr[2] x kk[2] -> acc[8][2].
//
// z (g>>8) selects input set; mode: z==0 -> mode_z0 (0=qk scatter, 1=fp32
// row-major), z==1 -> 0, z==2 -> 2 (V^T sigma scatter). XCD swizzle: grid
// x=8 (dispatch id%8 = x), each XCD owns a contiguous g-range -> A-panel
// L2 reuse across its 8 nb blocks.
// ---------------------------------------------------------------------------
__global__ __launch_bounds__(512) void gemm256_kernel(
    const unsigned short* __restrict__ A0, const unsigned short* __restrict__ A1,
    const unsigned short* __restrict__ A2,
    const unsigned short* __restrict__ Bt0, const unsigned short* __restrict__ Bt1,
    const unsigned short* __restrict__ Bt2,
    void* __restrict__ C0, void* __restrict__ C1, void* __restrict__ C2,
    int mode_z0, float scale_z0) {
  constexpr int K = 1024;
  __shared__ __align__(16) unsigned short As[2][256 * 64];  // 2 x 32 KB
  __shared__ __align__(16) unsigned short Bs[2][128 * 64];  // 2 x 16 KB

  const int tid  = threadIdx.x;
  const int wave = tid >> 6, lane = tid & 63;
  const int quad = lane >> 4, l16 = lane & 15;
  const int wm = wave >> 2, wn = wave & 3;   // 2M x 4N wave grid

  const int g  = blockIdx.x * gridDim.y + blockIdx.y;   // XCD-contiguous id
  const int z  = g >> 8;                                 // 256 blocks per z
  const int rz = g & 255;
  const int mb = rz >> 3, nb = rz & 7;
  const int m0 = mb * 256, n0 = nb * 128;

  const unsigned short* A  = z == 0 ? A0  : z == 1 ? A1  : A2;
  const unsigned short* BT = z == 0 ? Bt0 : z == 1 ? Bt1 : Bt2;
  void* Cout               = z == 0 ? C0  : z == 1 ? C1  : C2;
  const int   mode  = z == 0 ? mode_z0 : (z == 2 ? 2 : 0);
  const float scale = z == 0 ? scale_z0 : 1.0f;

  floatx4 acc[8][2] = {};

#define STAGE256(k0, buf)                                              \
  do {                                                                 \
    _Pragma("unroll")                                                  \
    for (int p = 0; p < 4; p++) {                                      \
      int si = p * 512 + tid;                                          \
      int rr = si >> 3;                                                \
      int gc = (si & 7) ^ (rr & 7);                                    \
      gload_lds16(A + (size_t)(m0 + rr) * K + (k0) + gc * 8,           \
                  As[buf] + (size_t)(p * 512 + wave * 64) * 8);        \
    }                                                                  \
    _Pragma("unroll")                                                  \
    for (int p = 0; p < 2; p++) {                                      \
      int si = p * 512 + tid;                                          \
      int rr = si >> 3;                                                \
      int gc = (si & 7) ^ (rr & 7);                                    \
      gload_lds16(BT + (size_t)(n0 + rr) * K + (k0) + gc * 8,          \
                  Bs[buf] + (size_t)(p * 512 + wave * 64) * 8);        \
    }                                                                  \
  } while (0)

  // prologue: stage k-tile 0 into buffer 0
  STAGE256(0, 0);

  int cur = 0;
  for (int k0 = 0; k0 < K; k0 += 64) {
    // One barrier per iter: drains loads issued last iter (covered by the
    // full compute phase) and orders reads of buf[cur^1] before overwrite.
    __syncthreads();

    if (k0 + 64 < K) STAGE256(k0 + 64, cur ^ 1);

    short8 bfr[2][2];
#pragma unroll
    for (int n = 0; n < 2; n++)
#pragma unroll
      for (int kk = 0; kk < 2; kk++) {
        int rb = wn * 32 + n * 16 + l16;
        int j = kk * 4 + quad;                       // chunk = col/8
        bfr[n][kk] = *(const short8*)(Bs[cur] + rb * 64 + (j ^ (rb & 7)) * 8);
      }
#pragma unroll
    for (int f = 0; f < 8; f++) {
      int ra = wm * 128 + f * 16 + l16;
      short8 a0 = *(const short8*)(As[cur] + ra * 64 + ((quad)     ^ (ra & 7)) * 8);
      short8 a1 = *(const short8*)(As[cur] + ra * 64 + ((4 + quad) ^ (ra & 7)) * 8);
#pragma unroll
      for (int n = 0; n < 2; n++) {
        acc[f][n] = mfma_bf16(a0, bfr[n][0], acc[f][n]);
        acc[f][n] = mfma_bf16(a1, bfr[n][1], acc[f][n]);
      }
    }
    cur ^= 1;
  }
#undef STAGE256

  // epilogue
#pragma unroll
  for (int f = 0; f < 8; f++)
#pragma unroll
    for (int n = 0; n < 2; n++)
#pragma unroll
      for (int r = 0; r < 4; r++) {
        int gm = m0 + wm * 128 + f * 16 + quad * 4 + r;
        int gn = n0 + wn * 32 + n * 16 + l16;
        float val = acc[f][n][r] * scale;
        if (mode == 0) {
          int b = gm >> 11, s = gm & 2047;
          int h = gn >> 6,  d = gn & 63;
          ((unsigned short*)Cout)[((size_t)((b * H_ + h) * S_ + s) << 6) + d] = f2bf(val);
        } else if (mode == 1) {
          ((float*)Cout)[((size_t)gm << 10) + gn] = val;
        } else {
          int b = gm >> 11, s = gm & 2047;
          int h = gn >> 6,  d = gn & 63;
          int p = ((s & 63) >> 4) + (s & 15) * 4;   // inv_sigma within 64-block
          ((unsigned short*)Cout)[(((size_t)(b * H_ + h) * 64 + d) << 11) + (s & ~63) + p] = f2bf(val);
        }
      }
}

// ---------------------------------------------------------------------------
// Flash attention v4: no-max exp2 softmax, V pre-transposed+sigma-permuted
// ([B,H,64,S]), K and V^T staged via XOR-swizzled global_load_lds.
// Double-buffered K/V LDS, one barrier per iter; raw v_exp_f32.
// ---------------------------------------------------------------------------
__global__ __launch_bounds__(512, 4) void attn_kernel(const unsigned short* __restrict__ q,
                                                      const unsigned short* __restrict__ k,
                                                      const unsigned short* __restrict__ vT,
                                                      unsigned short* __restrict__ X) {
  __shared__ unsigned short Ks[2][64 * 64];   // 2 x 8 KB, XOR-swizzled chunks
  __shared__ unsigned short Vt[2][64 * 64];   // 2 x 8 KB, XOR-swizzled chunks
  __shared__ unsigned short Ps[8][16 * 72];   // 18 KB, per-wave P tile, padded

  const int tid  = threadIdx.x;
  const int wave = tid >> 6, lane = tid & 63;
  const int quad = lane >> 4, l16 = lane & 15;
  // XCD-aware remap (bijective on 8x64 grid)
  const int bh = blockIdx.x * 8 + (blockIdx.y >> 3);
  const int q0 = (blockIdx.y & 7) * 256;

  const unsigned short* qh = q  + (size_t)bh * S_ * 64;
  const unsigned short* kh = k  + (size_t)bh * S_ * 64;
  const unsigned short* vh = vT + (size_t)bh * 64 * S_;   // [d][s']

  // staging pattern: 512 lanes x 16B = full 8 KB tile; chunk c of row r at
  // slot c^(r&7)
  const int sr  = tid >> 3;
  const int sgc = (tid & 7) ^ (sr & 7);

  // Q fragments (A-layout), resident: 2 qt x 2 k-chunks
  short8 qf[2][2];
  for (int qt = 0; qt < 2; qt++) {
    int row = q0 + wave * 32 + qt * 16 + l16;
    for (int kk = 0; kk < 2; kk++)
      qf[qt][kk] = *(const short8*)(qh + (size_t)row * 64 + kk * 32 + quad * 8);
  }

  // ones-column B-frag: B[k][n] = (n==0) ? 1 : 0
  short8 onesb = {};
  if (l16 == 0)
    for (int e = 0; e < 8; e++) onesb[e] = (short)0x3F80;

  const floatx4 fz = {};   // hoisted zero for per-iter score accumulators
  floatx4 O[2][4] = {};
  floatx4 lacc[2] = {};

  // prologue: stage tile 0 into buffer 0
  gload_lds16(kh + (size_t)sr * 64 + sgc * 8,       Ks[0] + (size_t)(wave * 64) * 8);
  gload_lds16(vh + (size_t)sr * S_ + 0 + sgc * 8,   Vt[0] + (size_t)(wave * 64) * 8);

  int cur = 0;
  for (int j0 = 0; j0 < S_; j0 += 64) {
    // One barrier per iter: drains last iter's loads (covered by the whole
    // compute phase) and orders reads of buf[cur^1] before its overwrite.
    __syncthreads();

    // issue next tile's stage early (overlaps with this iter's compute)
    if (j0 + 64 < S_) {
      int nxt = cur ^ 1;
      gload_lds16(kh + (size_t)(j0 + 64 + sr) * 64 + sgc * 8,
                  Ks[nxt] + (size_t)(wave * 64) * 8);
      gload_lds16(vh + (size_t)sr * S_ + (j0 + 64) + sgc * 8,
                  Vt[nxt] + (size_t)(wave * 64) * 8);
    }

    // K frags (B-layout: n=j=jf*16+l16, k=d): undo swizzle
    short8 kf[4][2];
    for (int jf = 0; jf < 4; jf++)
      for (int kk = 0; kk < 2; kk++) {
        int sl = (kk * 4 + quad) ^ (l16 & 7);
        kf[jf][kk] = *(const short8*)(Ks[cur] + (jf * 16 + l16) * 64 + sl * 8);
      }

    unsigned short* pw = Ps[wave];
    short8 pa[2][2];
    for (int qt = 0; qt < 2; qt++) {
      floatx4 s[4];
      for (int jf = 0; jf < 4; jf++) {
        s[jf] = mfma_bf16(qf[qt][0], kf[jf][0], fz);
        s[jf] = mfma_bf16(qf[qt][1], kf[jf][1], s[jf]);
      }
      // p = exp2(score) (q pre-scaled by log2e/sqrt(dk)); raw v_exp_f32,
      // RTZ-pack to bf16. Lane's 4 jf-values land at sigma positions 4*l16+jf.
      for (int r = 0; r < 4; r++) {
        float e0 = __builtin_amdgcn_exp2f(s[0][r]);
        float e1 = __builtin_amdgcn_exp2f(s[1][r]);
        float e2 = __builtin_amdgcn_exp2f(s[2][r]);
        float e3 = __builtin_amdgcn_exp2f(s[3][r]);
        uint2 pk;
        pk.x = pack_bf2(e0, e1);
        pk.y = pack_bf2(e2, e3);
        *(uint2*)(pw + (quad * 4 + r) * 72 + l16 * 4) = pk;
      }
      pa[qt][0] = *(const short8*)(pw + l16 * 72 + quad * 8);
      pa[qt][1] = *(const short8*)(pw + l16 * 72 + 32 + quad * 8);
      lacc[qt] = mfma_bf16(pa[qt][0], onesb, lacc[qt]);
      lacc[qt] = mfma_bf16(pa[qt][1], onesb, lacc[qt]);
    }

    // PV: V frags loaded per-df (8 VGPRs live at a time)
    for (int df = 0; df < 4; df++) {
      int sl0 = quad ^ (l16 & 7);
      int sl1 = (4 + quad) ^ (l16 & 7);
      short8 v0 = *(const short8*)(Vt[cur] + (df * 16 + l16) * 64 + sl0 * 8);
      short8 v1 = *(const short8*)(Vt[cur] + (df * 16 + l16) * 64 + sl1 * 8);
      for (int qt = 0; qt < 2; qt++) {
        O[qt][df] = mfma_bf16(pa[qt][0], v0, O[qt][df]);
        O[qt][df] = mfma_bf16(pa[qt][1], v1, O[qt][df]);
      }
    }
    cur ^= 1;
  }

  // epilogue: l lives in lane quad*16 (col 0), reg r; broadcast, divide, store
  const int b = bh >> 4, h = bh & 15;
  for (int qt = 0; qt < 2; qt++)
    for (int r = 0; r < 4; r++) {
      float lsum = __shfl(lacc[qt][r], (lane & 48));
      float inv = 1.0f / lsum;
      int row = q0 + wave * 32 + qt * 16 + quad * 4 + r;
      unsigned short* dst = X + ((size_t)(b * S_ + row) << 10) + h * 64;
      for (int df = 0; df < 4; df++)
        dst[df * 16 + l16] = f2bf(O[qt][df][r] * inv);
    }
}

// ---------------------------------------------------------------------------
extern "C" void kernel_launch(void* const* d_in, const int* in_sizes, int n_in,
                              void* d_out, int out_size, void* d_ws, size_t ws_size,
                              hipStream_t stream) {
  const float* Q  = (const float*)d_in[0];
  const float* K  = (const float*)d_in[1];
  const float* V  = (const float*)d_in[2];
  const float* wq = (const float*)d_in[3];
  const float* wk = (const float*)d_in[4];
  const float* wv = (const float*)d_in[5];
  const float* wo = (const float*)d_in[6];

  char* ws = (char*)d_ws;
  unsigned short* buf0 = (unsigned short*)ws;                        // 16 MB (vB cast, then attn X)
  unsigned short* wqT  = (unsigned short*)(ws + (size_t)(16 << 20));
  unsigned short* wkT  = (unsigned short*)(ws + (size_t)(18 << 20));
  unsigned short* wvT  = (unsigned short*)(ws + (size_t)(20 << 20));
  unsigned short* woT  = (unsigned short*)(ws + (size_t)(22 << 20));
  unsigned short* qP   = (unsigned short*)(ws + (size_t)(24 << 20));  // [B,H,S,64]
  unsigned short* kP   = (unsigned short*)(ws + (size_t)(40 << 20));  // [B,H,S,64]
  unsigned short* vTg  = (unsigned short*)(ws + (size_t)(56 << 20));  // [B,H,64,S] sigma

  // d_out (32 MB fp32) doubles as bf16 cast scratch for Q and K; it is dead
  // until the final wo-GEMM overwrites all of it.
  unsigned short* qB = (unsigned short*)d_out;             // 16 MB
  unsigned short* kB = qB + (size_t)8 * 1024 * 1024;       // 16 MB
  unsigned short* vB = buf0;                               // 16 MB (dead after proj)

  const float SC = 0.18033688011112043f;   // log2(e) / sqrt(64), folded into q

  wt_kernel<<<dim3(16, 16, 4), dim3(256), 0, stream>>>(wq, wk, wv, wo, wqT, wkT, wvT, woT);

  cast3_kernel<<<dim3(2048, 1, 3), dim3(256), 0, stream>>>(Q, K, V, qB, kB, vB);

  // projections: 768 blocks (3 full rounds at 1 block/CU), z = g>>8
  gemm256_kernel<<<dim3(8, 96), dim3(512), 0, stream>>>(
      qB, kB, vB, wqT, wkT, wvT, qP, kP, vTg, /*mode_z0=*/0, SC);

  attn_kernel<<<dim3(8, 64), dim3(512), 0, stream>>>(qP, kP, vTg, buf0);

  // output projection: 256 blocks (1 full round), fp32 row-major out
  gemm256_kernel<<<dim3(8, 32), dim3(512), 0, stream>>>(
      buf0, buf0, buf0, woT, woT, woT, d_out, d_out, d_out, /*mode_z0=*/1, 1.0f);
}